// Round 6
// baseline (627.097 us; speedup 1.0000x reference)
//
#include <hip/hip_runtime.h>
#include <hip/hip_bf16.h>

typedef __attribute__((ext_vector_type(4))) float floatx4;
typedef __attribute__((ext_vector_type(8))) short bf16x8;

__device__ __forceinline__ unsigned short f2bf(float f) {
    union { float f; unsigned u; } v; v.f = f;
    unsigned r = v.u + 0x7fffu + ((v.u >> 16) & 1u);  // RNE
    return (unsigned short)(r >> 16);
}

// fp32x8 -> bf16x8 via scalar casts; compiler fuses pairs into
// v_cvt_pk_bf16_f32 (m240: scalar cast beats hand-written cvt_pk).
__device__ __forceinline__ bf16x8 cvt8(float4 lo, float4 hi) {
    union { __hip_bfloat16 b[8]; bf16x8 v; } u;
    u.b[0] = __float2bfloat16(lo.x); u.b[1] = __float2bfloat16(lo.y);
    u.b[2] = __float2bfloat16(lo.z); u.b[3] = __float2bfloat16(lo.w);
    u.b[4] = __float2bfloat16(hi.x); u.b[5] = __float2bfloat16(hi.y);
    u.b[6] = __float2bfloat16(hi.z); u.b[7] = __float2bfloat16(hi.w);
    return u.v;
}

// async 16B/lane global->LDS DMA. lds dest = uniform base + lane*16.
__device__ __forceinline__ void dma16(const void* gsrc, void* ldst) {
    __builtin_amdgcn_global_load_lds(
        (const __attribute__((address_space(1))) unsigned*)gsrc,
        (__attribute__((address_space(3))) unsigned*)ldst, 16, 0, 0);
}

// ---------------------------------------------------------------------------
// prep: pack weights into MFMA B-operand fragment blobs (bf16) + fuse biases.
// Wcat blob [kc=0..47][ntg=0..31][lane=0..63][j=0..7]:
//   element B[k][n], k = kc*32 + (lane>>4)*8 + j, n = ntg*16 + (lane&15)
//   k < 1024 -> W1[c][k][s] (c=n>>5, s=n&31), else W2[c][k-1024][s]
// W3 blob   [kc=0..15][ntg=0..31][lane][j]: B[k][n] = W3flat[k*512 + n]
// bias12[n] = b1flat[n] + b2flat[n];  bias3s[n] = sum_c b3[c*512+n]
// ---------------------------------------------------------------------------
__global__ void prep_kernel(const float* __restrict__ W1, const float* __restrict__ b1,
                            const float* __restrict__ W2, const float* __restrict__ b2,
                            const float* __restrict__ W3, const float* __restrict__ b3,
                            unsigned short* __restrict__ wcat, unsigned short* __restrict__ w3f,
                            float* __restrict__ bias12, float* __restrict__ bias3s)
{
    int tid = blockIdx.x * 256 + threadIdx.x;
    if (tid < 98304) {                       // 48 * 32 * 64 fragment-lanes
        int l  = tid & 63;
        int nt = (tid >> 6) & 31;
        int kc = tid >> 11;                  // 0..47
        int n  = nt * 16 + (l & 15);
        int k0 = kc * 32 + ((l >> 4) << 3);
        int c = n >> 5, s = n & 31;
        union { unsigned short us[8]; int4 v; } pk;
        const float* src = (k0 < 1024) ? (W1 + c * 32768 + k0 * 32 + s)
                                       : (W2 + c * 16384 + (k0 - 1024) * 32 + s);
        #pragma unroll
        for (int j = 0; j < 8; ++j) pk.us[j] = f2bf(src[j * 32]);
        *(int4*)(wcat + (size_t)tid * 8) = pk.v;
    } else if (tid < 131072) {               // 16 * 32 * 64 fragment-lanes for W3
        int t  = tid - 98304;
        int l  = t & 63;
        int nt = (t >> 6) & 31;
        int kc = t >> 11;                    // 0..15
        int n  = nt * 16 + (l & 15);
        int k0 = kc * 32 + ((l >> 4) << 3);
        union { unsigned short us[8]; int4 v; } pk;
        const float* src = W3 + k0 * 512 + n;
        #pragma unroll
        for (int j = 0; j < 8; ++j) pk.us[j] = f2bf(src[j * 512]);
        *(int4*)(w3f + (size_t)t * 8) = pk.v;
    } else if (tid < 131584) {
        int n = tid - 131072;
        bias12[n] = b1[n] + b2[n];
        float sacc = 0.f;
        #pragma unroll
        for (int c = 0; c < 16; ++c) sacc += b3[c * 512 + n];
        bias3s[n] = sacc;
    }
}

// ---------------------------------------------------------------------------
// fused main: 64 rows/block, 512 threads = 8 waves, wave w owns cols
// [w*64, w*64+64). Phase 1 = 24 periods of BK=64, one plain s_barrier each.
// A-staging via global_load_lds DMA (fp32, no VGPR round trip, no f2bf,
// no ds_write, no lgkm drain), TRIPLE buffered: DMA for period p+2 issued
// in body p -> one full period in flight. Counted vmcnt (never 0):
//   steady-state end-of-body wait = vmcnt(10)  [bcur(p+1)=8 + DMA(p+2)=2
//   younger than the DMA(p+1) pair we need landed]. Peeled: p=22 ->
//   vmcnt(8); p=23 -> no wait.
// LDS As32[3][region=8][h=2][lane=64][4 floats] (48 KB):
//   region F = half*4+mt (2 KB), staged by wave W=F; DMA lane l, issue h
//   writes floats A[row=rowbase+mt*16+(l&15)]
//                [col=t*64+half*32+(l>>4)*8+h*4 ..+3] at F*2048+h*1024+l*16.
//   Fragment read: lane l reads lo=h0/hi=h1 float4 at l*16 -> cvt8 -> bf16x8
//   (A-frag: lane l holds A[m=l&15][k=(l>>4)*8+j]).
// B-frags (bcur) reloaded in a batch after the MFMA clusters (in flight
// across the barrier, compiler-counted vmcnt at next use).
// Union with Hf (64 KB) -> LDS 65536 B, 2 blocks/CU.
// MFMA 16x16x32 bf16; B-frag: B[k=(l>>4)*8+j][n=l&15]; C/D: col=l&15,
// row=(l>>4)*4+reg.
// ---------------------------------------------------------------------------
__global__ __launch_bounds__(512, 4) void fused_main(
    const float* __restrict__ app, const float* __restrict__ sp,
    const unsigned short* __restrict__ wcat, const unsigned short* __restrict__ w3f,
    const float* __restrict__ bias12, const float* __restrict__ bias3s,
    float* __restrict__ out)
{
    __shared__ union {
        float          As32[3][8][2][64][4];   // 48 KB fp32 A staging (3-buf)
        unsigned short Hf[4][16][64][8];       // 64 KB H in A-frag layout
    } sh;
    char* shb = (char*)&sh;

    const int tid = (int)threadIdx.x;
    const int w   = tid >> 6;                 // 0..7
    const int l   = tid & 63;
    const int rowbase = (int)blockIdx.x * 64;

    // per-lane DMA global source bases (wave w stages region F = w)
    const int half = w >> 2, mtw = w & 3;
    const int grow = rowbase + mtw * 16 + (l & 15);
    const char* appB = (const char*)app + (size_t)grow * 4096 + half * 128 + (l >> 4) * 32;
    const char* spB  = (const char*)sp  + (size_t)grow * 2048 + half * 128 + (l >> 4) * 32;

    #define DMA_T(t) do {                                                     \
        const char* _g = ((t) < 16) ? (appB + (t) * 256)                      \
                                    : (spB + ((t) - 16) * 256);               \
        char* _d = shb + ((t) % 3) * 16384 + w * 2048;                        \
        dma16(_g,      _d);                                                   \
        dma16(_g + 16, _d + 1024);                                            \
    } while (0)

    #define BLOAD(kp) do {                                                    \
        const unsigned short* _wp = wbase + (size_t)(kp) * 32768;             \
        _Pragma("unroll")                                                     \
        for (int i = 0; i < 8; ++i)                                           \
            bcur[i] = *(const bf16x8*)(_wp + (i >> 2) * 16384 + (i & 3) * 512);\
    } while (0)

    #define PERIOD_CORE(p) do {                                               \
        const int _bo = ((p) % 3) * 16384;                                    \
        bf16x8 af[4];                                                         \
        _Pragma("unroll")                                                     \
        for (int mt = 0; mt < 4; ++mt) {                                      \
            float4 lo = *(const float4*)(shb + _bo + mt * 2048 + l * 16);     \
            float4 hi = *(const float4*)(shb + _bo + mt * 2048 + 1024 + l * 16);\
            af[mt] = cvt8(lo, hi);                                            \
        }                                                                     \
        __builtin_amdgcn_s_setprio(1);                                        \
        _Pragma("unroll")                                                     \
        for (int mt = 0; mt < 4; ++mt)                                        \
            _Pragma("unroll")                                                 \
            for (int nt = 0; nt < 4; ++nt)                                    \
                acc[mt][nt] = __builtin_amdgcn_mfma_f32_16x16x32_bf16(        \
                    af[mt], bcur[nt], acc[mt][nt], 0, 0, 0);                  \
        __builtin_amdgcn_s_setprio(0);                                        \
        _Pragma("unroll")                                                     \
        for (int mt = 0; mt < 4; ++mt) {                                      \
            float4 lo = *(const float4*)(shb + _bo + (4 + mt) * 2048 + l * 16);\
            float4 hi = *(const float4*)(shb + _bo + (4 + mt) * 2048 + 1024 + l * 16);\
            af[mt] = cvt8(lo, hi);                                            \
        }                                                                     \
        __builtin_amdgcn_s_setprio(1);                                        \
        _Pragma("unroll")                                                     \
        for (int mt = 0; mt < 4; ++mt)                                        \
            _Pragma("unroll")                                                 \
            for (int nt = 0; nt < 4; ++nt)                                    \
                acc[mt][nt] = __builtin_amdgcn_mfma_f32_16x16x32_bf16(        \
                    af[mt], bcur[4 + nt], acc[mt][nt], 0, 0, 0);              \
        __builtin_amdgcn_s_setprio(0);                                        \
    } while (0)

    floatx4 acc[4][4];
    #pragma unroll
    for (int mt = 0; mt < 4; ++mt)
        #pragma unroll
        for (int nt = 0; nt < 4; ++nt)
            acc[mt][nt] = (floatx4){0.f, 0.f, 0.f, 0.f};

    const unsigned short* wbase = wcat + (size_t)w * 2048 + (size_t)l * 8;

    // prologue: bcur(0) [8 loads], DMA(0) [2], DMA(1) [2];
    // wait vmcnt(2): bcur(0)+DMA(0) landed, DMA(1) still in flight.
    bf16x8 bcur[8];
    BLOAD(0);
    DMA_T(0);
    DMA_T(1);
    asm volatile("s_waitcnt vmcnt(2)" ::: "memory");
    __builtin_amdgcn_s_barrier();
    asm volatile("" ::: "memory");

    // ---- phase 1: H_pre = [app|sp] @ Wcat, K = 1536 (24 periods of 64) ----
    for (int p = 0; p < 22; ++p) {
        PERIOD_CORE(p);
        BLOAD(p + 1);
        DMA_T(p + 2);
        // need DMA(p+1) landed; younger: bcur(p+1)=8 + DMA(p+2)=2
        asm volatile("s_waitcnt vmcnt(10)" ::: "memory");
        __builtin_amdgcn_s_barrier();
        asm volatile("" ::: "memory");
    }
    // p = 22: no DMA(24); need DMA(23) landed; younger: bcur(23)=8
    PERIOD_CORE(22);
    BLOAD(23);
    asm volatile("s_waitcnt vmcnt(8)" ::: "memory");
    __builtin_amdgcn_s_barrier();
    asm volatile("" ::: "memory");
    // p = 23: last period; no staging, no wait; barrier before Hf overwrite
    PERIOD_CORE(23);
    __builtin_amdgcn_s_barrier();
    asm volatile("" ::: "memory");

    // ---- phase-3 W3 prefetch (before phase-2 writes; vmcnt survives) ----
    const unsigned short* w3base = w3f + (size_t)w * 2048 + (size_t)l * 8;
    bf16x8 b3[8];
    #pragma unroll
    for (int i = 0; i < 8; ++i)
        b3[i] = *(const bf16x8*)(w3base + (i >> 2) * 16384 + (i & 3) * 512);

    // ---- phase 2: relu + bias, write Hf in A-frag layout (clobbers As32) --
    #pragma unroll
    for (int nt = 0; nt < 4; ++nt) {
        const int colg = w * 64 + nt * 16 + (l & 15);
        const float bv = bias12[colg];
        const int kc  = colg >> 5;
        const int lhi = ((colg >> 3) & 3) << 4;
        const int j   = colg & 7;
        #pragma unroll
        for (int mt = 0; mt < 4; ++mt)
            #pragma unroll
            for (int r = 0; r < 4; ++r) {
                const int rlow = ((l >> 4) << 2) + r;      // rowg & 15
                float v = acc[mt][nt][r] + bv;
                v = fmaxf(v, 0.f);
                sh.Hf[mt][kc][lhi + rlow][j] = f2bf(v);
            }
    }
    asm volatile("s_waitcnt lgkmcnt(0)" ::: "memory");
    __builtin_amdgcn_s_barrier();
    asm volatile("" ::: "memory");

    // ---- phase 3: out = relu(Hf @ W3 + bias3s), K = 512, NO barriers ----
    #pragma unroll
    for (int mt = 0; mt < 4; ++mt)
        #pragma unroll
        for (int nt = 0; nt < 4; ++nt)
            acc[mt][nt] = (floatx4){0.f, 0.f, 0.f, 0.f};

    for (int q = 0; q < 8; ++q) {
        bf16x8 af[4];
        #pragma unroll
        for (int mt = 0; mt < 4; ++mt)
            af[mt] = *(const bf16x8*)(&sh.Hf[mt][2 * q][l][0]);
        __builtin_amdgcn_s_setprio(1);
        #pragma unroll
        for (int mt = 0; mt < 4; ++mt)
            #pragma unroll
            for (int nt = 0; nt < 4; ++nt)
                acc[mt][nt] = __builtin_amdgcn_mfma_f32_16x16x32_bf16(
                    af[mt], b3[nt], acc[mt][nt], 0, 0, 0);
        __builtin_amdgcn_s_setprio(0);
        #pragma unroll
        for (int mt = 0; mt < 4; ++mt)
            af[mt] = *(const bf16x8*)(&sh.Hf[mt][2 * q + 1][l][0]);
        __builtin_amdgcn_s_setprio(1);
        #pragma unroll
        for (int mt = 0; mt < 4; ++mt)
            #pragma unroll
            for (int nt = 0; nt < 4; ++nt)
                acc[mt][nt] = __builtin_amdgcn_mfma_f32_16x16x32_bf16(
                    af[mt], b3[4 + nt], acc[mt][nt], 0, 0, 0);
        __builtin_amdgcn_s_setprio(0);
        if (q + 1 < 8) {
            const unsigned short* wp = w3base + (size_t)(q + 1) * 32768;
            #pragma unroll
            for (int i = 0; i < 8; ++i)
                b3[i] = *(const bf16x8*)(wp + (i >> 2) * 16384 + (i & 3) * 512);
        }
    }

    // ---- epilogue ----
    #pragma unroll
    for (int nt = 0; nt < 4; ++nt) {
        const int colg = w * 64 + nt * 16 + (l & 15);
        const float bv = bias3s[colg];
        #pragma unroll
        for (int mt = 0; mt < 4; ++mt)
            #pragma unroll
            for (int r = 0; r < 4; ++r) {
                const int rowg = mt * 16 + ((l >> 4) << 2) + r;
                float v = acc[mt][nt][r] + bv;
                v = fmaxf(v, 0.f);
                out[(size_t)(rowbase + rowg) * 512 + colg] = v;
            }
    }
    #undef PERIOD_CORE
    #undef BLOAD
    #undef DMA_T
}

extern "C" void kernel_launch(void* const* d_in, const int* in_sizes, int n_in,
                              void* d_out, int out_size, void* d_ws, size_t ws_size,
                              hipStream_t stream)
{
    const float* app = (const float*)d_in[0];
    const float* sp  = (const float*)d_in[1];
    const float* W1  = (const float*)d_in[2];
    const float* b1  = (const float*)d_in[3];
    const float* W2  = (const float*)d_in[4];
    const float* b2  = (const float*)d_in[5];
    const float* W3  = (const float*)d_in[6];
    const float* b3  = (const float*)d_in[7];

    char* ws = (char*)d_ws;
    unsigned short* wcat  = (unsigned short*)(ws);             // 1,572,864 B
    unsigned short* w3f   = (unsigned short*)(ws + 1572864);   //   524,288 B
    float*          b12   = (float*)(ws + 2097152);            //     2,048 B
    float*          b3s   = (float*)(ws + 2099200);            //     2,048 B

    prep_kernel<<<514, 256, 0, stream>>>(W1, b1, W2, b2, W3, b3, wcat, w3f, b12, b3s);

    float* outp = (float*)d_out;
    fused_main<<<65536 / 64, 512, 0, stream>>>(app, sp, wcat, w3f, b12, b3s, outp);
}